// Round 8
// baseline (173.948 us; speedup 1.0000x reference)
//
#include <hip/hip_runtime.h>
#include <hip/hip_bf16.h>
#include <cstdint>

#define B_   2
#define T_   2048
#define C_   1024
#define NH_  16
#define HS_  64
#define WIN_ 256
#define M_   (B_*T_)   // 4096

typedef __attribute__((ext_vector_type(8)))  short          short8;
typedef __attribute__((ext_vector_type(8)))  unsigned short ushortx8;
typedef __attribute__((ext_vector_type(8)))  __bf16         bf16x8;
typedef __attribute__((ext_vector_type(4)))  float          floatx4;
typedef __attribute__((ext_vector_type(16))) float          floatx16;

__device__ __forceinline__ unsigned short f2bf(float f) {
    union { float f; uint32_t u; } v; v.f = f;
    uint32_t r = (v.u + 0x7FFFu + ((v.u >> 16) & 1u)) >> 16;
    return (unsigned short)r;
}

__device__ __forceinline__ floatx4 mfma16(short8 a, short8 b, floatx4 c) {
    return __builtin_amdgcn_mfma_f32_16x16x32_bf16(
        __builtin_bit_cast(bf16x8, a), __builtin_bit_cast(bf16x8, b), c, 0, 0, 0);
}
__device__ __forceinline__ floatx16 mfma32(short8 a, short8 b, floatx16 c) {
    return __builtin_amdgcn_mfma_f32_32x32x16_bf16(
        __builtin_bit_cast(bf16x8, a), __builtin_bit_cast(bf16x8, b), c, 0, 0, 0);
}

__device__ __forceinline__ void async16(const void* g, void* l) {
    __builtin_amdgcn_global_load_lds(
        (const __attribute__((address_space(1))) void*)g,
        (__attribute__((address_space(3))) void*)l, 16, 0, 0);
}

// ---------------------------------------------------------------------------
// Fused prep (x convert + both weight transposes)
// ---------------------------------------------------------------------------
#define NB_CONV 4096
#define NB_WA   768
#define NB_WP   256

__device__ void transpose_tile(const float* __restrict__ in, unsigned short* __restrict__ out,
                               int K, int N, int kt, int nt, unsigned short (*tile)[65])
{
    const int k0 = kt * 64, n0 = nt * 64;
    const int tr = threadIdx.x >> 4;
    const int tc = (threadIdx.x & 15) * 4;
    #pragma unroll
    for (int it = 0; it < 4; it++) {
        int row = tr + it * 16;
        float4 v = *(const float4*)&in[(size_t)(k0 + row) * N + n0 + tc];
        tile[row][tc + 0] = f2bf(v.x);
        tile[row][tc + 1] = f2bf(v.y);
        tile[row][tc + 2] = f2bf(v.z);
        tile[row][tc + 3] = f2bf(v.w);
    }
    __syncthreads();
    #pragma unroll
    for (int it = 0; it < 4; it++) {
        int nrow = tr + it * 16;
        ushort4 h;
        h.x = tile[tc + 0][nrow]; h.y = tile[tc + 1][nrow];
        h.z = tile[tc + 2][nrow]; h.w = tile[tc + 3][nrow];
        *(ushort4*)&out[(size_t)(n0 + nrow) * K + k0 + tc] = h;
    }
}

__global__ __launch_bounds__(256)
void prep_kernel(const float* __restrict__ x, const float* __restrict__ W_attn,
                 const float* __restrict__ W_proj,
                 unsigned short* __restrict__ xb, unsigned short* __restrict__ Wa_t,
                 unsigned short* __restrict__ Wp_t)
{
    __shared__ unsigned short tile[64][65];
    const int bid = blockIdx.x;
    if (bid < NB_CONV) {
        int i = (bid * 256 + threadIdx.x) * 4;
        float4 v = *(const float4*)&x[i];
        ushort4 h;
        h.x = f2bf(v.x); h.y = f2bf(v.y); h.z = f2bf(v.z); h.w = f2bf(v.w);
        *(ushort4*)&xb[i] = h;
    } else if (bid < NB_CONV + NB_WA) {
        int idx = bid - NB_CONV;
        transpose_tile(W_attn, Wa_t, C_, 3 * C_, idx / 48, idx % 48, tile);
    } else {
        int idx = bid - NB_CONV - NB_WA;
        transpose_tile(W_proj, Wp_t, C_, C_, idx / 16, idx % 16, tile);
    }
}

// ---------------------------------------------------------------------------
// GEMM, 32x32x16 MFMA, BK=64, XOR-swizzled LDS (conflict-free, DMA-compatible)
// ---------------------------------------------------------------------------
template<int MT, bool OUT_BF16, bool VSPLIT>
__global__ __launch_bounds__(256)
void gemm32(const unsigned short* __restrict__ A,
            const unsigned short* __restrict__ Bt,
            void* __restrict__ Cp, unsigned short* __restrict__ vt,
            int M, int N, int K)
{
    constexpr int BK = 64;
    constexpr int BM = 64 * MT;
    __shared__ unsigned short As[BM * BK];
    __shared__ unsigned short Bs[128 * BK];

    const int tid  = threadIdx.x;
    const int lane = tid & 63;
    const int wave = tid >> 6;
    const int l32  = lane & 31;
    const int hi   = lane >> 5;
    const int px   = l32 & 7;
    const int wm   = (wave & 1) * 32 * MT;
    const int wn   = (wave >> 1) * 64;
    const int m0   = blockIdx.y * BM;
    const int n0   = blockIdx.x * 128;

    const int ri = lane >> 3;
    const int pg = lane & 7;
    const int gg = pg ^ ri;

    floatx16 acc[MT][2];
    #pragma unroll
    for (int i = 0; i < MT; i++)
        #pragma unroll
        for (int j = 0; j < 2; j++) acc[i][j] = (floatx16)(0.f);

    const unsigned short* gA = &A[(size_t)(m0 + wave * 8 + ri) * K + gg * 8];
    const unsigned short* gB = &Bt[(size_t)(n0 + wave * 8 + ri) * K + gg * 8];
    unsigned short* lA = &As[(wave * 8) * BK];
    unsigned short* lB = &Bs[(wave * 8) * BK];

    for (int k0 = 0; k0 < K; k0 += BK) {
        #pragma unroll
        for (int s = 0; s < 2 * MT; s++)
            async16(gA + k0 + (size_t)s * 32 * K, lA + s * 32 * BK);
        #pragma unroll
        for (int s = 0; s < 4; s++)
            async16(gB + k0 + (size_t)s * 32 * K, lB + s * 32 * BK);
        __syncthreads();

        #pragma unroll
        for (int ks = 0; ks < 4; ks++) {
            short8 af[MT], bfr[2];
            #pragma unroll
            for (int i = 0; i < MT; i++) {
                int r = wm + i * 32 + l32;
                int p = (ks * 2 + hi) ^ px;
                af[i] = *(const short8*)(&As[r * BK + p * 8]);
            }
            #pragma unroll
            for (int j = 0; j < 2; j++) {
                int r = wn + j * 32 + l32;
                int p = (ks * 2 + hi) ^ px;
                bfr[j] = *(const short8*)(&Bs[r * BK + p * 8]);
            }
            #pragma unroll
            for (int i = 0; i < MT; i++)
                #pragma unroll
                for (int j = 0; j < 2; j++)
                    acc[i][j] = mfma32(af[i], bfr[j], acc[i][j]);
        }
        __syncthreads();
    }

    #pragma unroll
    for (int i = 0; i < MT; i++)
        #pragma unroll
        for (int j = 0; j < 2; j++) {
            const int col  = n0 + wn + j * 32 + l32;
            const int row0 = m0 + wm + i * 32 + 4 * hi;
            if (VSPLIT && col >= 2 * C_) {
                const int hd = col - 2 * C_;
                const int hh = hd >> 6, d = hd & 63;
                #pragma unroll
                for (int g = 0; g < 4; g++) {
                    int rowg = row0 + 8 * g;
                    int bb = rowg >> 11, t = rowg & (T_ - 1);
                    ushort4 h4;
                    h4.x = f2bf(acc[i][j][g * 4 + 0]);
                    h4.y = f2bf(acc[i][j][g * 4 + 1]);
                    h4.z = f2bf(acc[i][j][g * 4 + 2]);
                    h4.w = f2bf(acc[i][j][g * 4 + 3]);
                    *(ushort4*)&vt[((size_t)(bb * NH_ + hh) * 64 + d) * T_ + t] = h4;
                }
            } else {
                #pragma unroll
                for (int g = 0; g < 4; g++)
                    #pragma unroll
                    for (int rr = 0; rr < 4; rr++) {
                        int row = row0 + 8 * g + rr;
                        if (OUT_BF16)
                            ((unsigned short*)Cp)[(size_t)row * N + col] = f2bf(acc[i][j][g * 4 + rr]);
                        else
                            ((float*)Cp)[(size_t)row * N + col] = acc[i][j][g * 4 + rr];
                    }
            }
        }
}

// ---------------------------------------------------------------------------
// Sliding-window attention. Wave-independent (16 q-rows/wave), barrier-free.
// XCD-aware swizzle: XCD (g&7) owns 4 (h,b) pairs, sweeps their q-tiles
// consecutively -> K/V window re-reads hit the per-XCD L2 (~1MB working set).
// Register ping-pong: K frags for tile t+1 issued before tile t's MFMAs;
// V frags issued at tile start, consumed after softmax+P roundtrip.
// No running max (scores bounded, masked -> exp underflows to 0).
// ---------------------------------------------------------------------------
__device__ __forceinline__ void load_kf(short8 kf[8], const unsigned short* kbase,
                                        int l16, int quad)
{
    #pragma unroll
    for (int nt = 0; nt < 4; nt++)
        #pragma unroll
        for (int ks = 0; ks < 2; ks++)
            kf[nt * 2 + ks] = *(const short8*)&kbase[(size_t)(nt * 16 + l16) * (3 * C_)
                                                     + ks * 32 + quad * 8];
}

__device__ __forceinline__ void load_vf(short8 vf[8], const unsigned short* vbase,
                                        int l16, int quad)
{
    #pragma unroll
    for (int jt = 0; jt < 4; jt++)
        #pragma unroll
        for (int ks = 0; ks < 2; ks++)
            vf[jt * 2 + ks] = *(const short8*)&vbase[(size_t)(jt * 16 + l16) * T_
                                                     + ks * 32 + quad * 8];
}

__device__ __forceinline__ void attn_tile(const short8 aq[2], const short8 kf[8],
                                          const short8 vf[8], int kb, int q0,
                                          int l16, int quad,
                                          unsigned short* Pstrip,
                                          floatx4 O[4], float psum[4])
{
    const float SC = 0.125f * 1.44269504f;
    floatx4 s[4];
    #pragma unroll
    for (int nt = 0; nt < 4; nt++) s[nt] = (floatx4){0.f, 0.f, 0.f, 0.f};
    #pragma unroll
    for (int ks = 0; ks < 2; ks++)
        #pragma unroll
        for (int nt = 0; nt < 4; nt++)
            s[nt] = mfma16(aq[ks], kf[nt * 2 + ks], s[nt]);

    #pragma unroll
    for (int nt = 0; nt < 4; nt++)
        #pragma unroll
        for (int r = 0; r < 4; r++) {
            int dist = (q0 + quad * 4 + r) - (kb + nt * 16 + l16);
            float sv = ((unsigned)dist < (unsigned)WIN_) ? s[nt][r] * SC : -1e30f;
            float e = exp2f(sv);
            psum[r] += e;
            s[nt][r] = e;
        }

    #pragma unroll
    for (int nt = 0; nt < 4; nt++)
        #pragma unroll
        for (int r = 0; r < 4; r++)
            Pstrip[(quad * 4 + r) * 72 + nt * 16 + l16] = f2bf(s[nt][r]);

    #pragma unroll
    for (int ks = 0; ks < 2; ks++) {
        short8 ap = *(const short8*)&Pstrip[l16 * 72 + ks * 32 + quad * 8];
        #pragma unroll
        for (int jt = 0; jt < 4; jt++)
            O[jt] = mfma16(ap, vf[jt * 2 + ks], O[jt]);
    }
}

__global__ __launch_bounds__(256)
void attn_kernel(const unsigned short* __restrict__ qkv,
                 const unsigned short* __restrict__ vt,
                 unsigned short* __restrict__ y)
{
    __shared__ unsigned short Ps[4][16 * 72];

    const int tid  = threadIdx.x;
    const int lane = tid & 63;
    const int wave = tid >> 6;
    const int l16  = lane & 15;
    const int quad = lane >> 4;

    // XCD-aware decode of flat grid (1024 blocks): xcd = g&7 (assumed),
    // hb = (g&7) + 8*((g>>3)>>5), qt = (g>>3)&31.
    const int g  = blockIdx.x;
    const int yq = g >> 3;
    const int hb = (g & 7) + 8 * (yq >> 5);
    const int qt = yq & 31;
    const int h  = hb & 15;
    const int b  = hb >> 4;

    const int q0 = qt * 64 + wave * 16;
    const size_t base = (size_t)b * T_;
    const int ROW  = 3 * C_;
    const int qoff = h * HS_;
    const int koff = C_ + h * HS_;
    const size_t vbase = ((size_t)(b * NH_ + h) * 64) * T_;
    unsigned short* Pstrip = Ps[wave];

    short8 aq[2];
    #pragma unroll
    for (int ks = 0; ks < 2; ks++)
        aq[ks] = *(const short8*)&qkv[(base + q0 + l16) * ROW + qoff + ks * 32 + quad * 8];

    floatx4 O[4];
    #pragma unroll
    for (int j = 0; j < 4; j++) O[j] = (floatx4){0.f, 0.f, 0.f, 0.f};
    float psum[4] = {0.f, 0.f, 0.f, 0.f};

    int kb_lo = q0 - (WIN_ - 1);
    kb_lo = (kb_lo > 0 ? kb_lo : 0) & ~63;
    const int kb_hi = qt * 64;

    const unsigned short* kgb = &qkv[base * ROW + koff];
    const unsigned short* vgb = &vt[vbase];

    short8 ka[8], kbb[8];
    load_kf(ka, kgb + (size_t)kb_lo * ROW, l16, quad);

    int kb = kb_lo;
    while (kb + 64 <= kb_hi) {
        load_kf(kbb, kgb + (size_t)(kb + 64) * ROW, l16, quad);
        {
            short8 vf[8];
            load_vf(vf, vgb + kb, l16, quad);
            attn_tile(aq, ka, vf, kb, q0, l16, quad, Pstrip, O, psum);
        }
        kb += 64;
        if (kb + 64 <= kb_hi)
            load_kf(ka, kgb + (size_t)(kb + 64) * ROW, l16, quad);
        {
            short8 vf[8];
            load_vf(vf, vgb + kb, l16, quad);
            attn_tile(aq, kbb, vf, kb, q0, l16, quad, Pstrip, O, psum);
        }
        kb += 64;
    }
    if (kb <= kb_hi) {
        short8 vf[8];
        load_vf(vf, vgb + kb, l16, quad);
        attn_tile(aq, ka, vf, kb, q0, l16, quad, Pstrip, O, psum);
    }

    #pragma unroll
    for (int r = 0; r < 4; r++) {
        #pragma unroll
        for (int off = 8; off >= 1; off >>= 1)
            psum[r] += __shfl_xor(psum[r], off, 64);
    }

    #pragma unroll
    for (int jt = 0; jt < 4; jt++)
        #pragma unroll
        for (int r = 0; r < 4; r++)
            Pstrip[(quad * 4 + r) * 72 + jt * 16 + l16] = f2bf(O[jt][r] / psum[r]);
    #pragma unroll
    for (int it = 0; it < 2; it++) {
        int c = lane + 64 * it;
        int qr = c >> 3, dc = (c & 7) * 8;
        *(ushortx8*)&y[(base + q0 + qr) * C_ + qoff + dc] =
            *(const ushortx8*)&Pstrip[qr * 72 + dc];
    }
}

// ---------------------------------------------------------------------------
extern "C" void kernel_launch(void* const* d_in, const int* in_sizes, int n_in,
                              void* d_out, int out_size, void* d_ws, size_t ws_size,
                              hipStream_t stream)
{
    const float* x      = (const float*)d_in[0];
    const float* W_attn = (const float*)d_in[1];
    const float* W_proj = (const float*)d_in[2];
    float* out = (float*)d_out;

    unsigned short* xb   = (unsigned short*)d_ws;                 // [M][C]      8 MB
    unsigned short* Wa_t = xb   + (size_t)M_ * C_;                // [3C][C]     6 MB
    unsigned short* Wp_t = Wa_t + (size_t)3 * C_ * C_;            // [C][C]      2 MB
    unsigned short* qkv  = Wp_t + (size_t)C_ * C_;                // [M][3C]    24 MB (Q,K)
    unsigned short* y    = qkv  + (size_t)M_ * 3 * C_;            // [M][C]      8 MB
    unsigned short* vtg  = y    + (size_t)M_ * C_;                // [B][NH][64][T] 8 MB

    dim3 blk(256);
    prep_kernel<<<NB_CONV + NB_WA + NB_WP, blk, 0, stream>>>(x, W_attn, W_proj, xb, Wa_t, Wp_t);
    gemm32<2, true, true><<<dim3((3 * C_) / 128, M_ / 128), blk, 0, stream>>>(
        xb, Wa_t, qkv, vtg, M_, 3 * C_, C_);
    attn_kernel<<<(T_ / 64) * NH_ * B_, blk, 0, stream>>>(qkv, vtg, y);
    gemm32<1, false, false><<<dim3(C_ / 128, M_ / 64), blk, 0, stream>>>(
        y, Wp_t, out, nullptr, M_, C_, C_);
}

// Round 9
// 150.811 us; speedup vs baseline: 1.1534x; 1.1534x over previous
//
#include <hip/hip_runtime.h>
#include <hip/hip_bf16.h>
#include <cstdint>

#define B_   2
#define T_   2048
#define C_   1024
#define NH_  16
#define HS_  64
#define WIN_ 256
#define M_   (B_*T_)   // 4096

typedef __attribute__((ext_vector_type(8)))  short          short8;
typedef __attribute__((ext_vector_type(8)))  unsigned short ushortx8;
typedef __attribute__((ext_vector_type(8)))  __bf16         bf16x8;
typedef __attribute__((ext_vector_type(4)))  float          floatx4;
typedef __attribute__((ext_vector_type(16))) float          floatx16;

__device__ __forceinline__ unsigned short f2bf(float f) {
    union { float f; uint32_t u; } v; v.f = f;
    uint32_t r = (v.u + 0x7FFFu + ((v.u >> 16) & 1u)) >> 16;
    return (unsigned short)r;
}

__device__ __forceinline__ floatx4 mfma16(short8 a, short8 b, floatx4 c) {
    return __builtin_amdgcn_mfma_f32_16x16x32_bf16(
        __builtin_bit_cast(bf16x8, a), __builtin_bit_cast(bf16x8, b), c, 0, 0, 0);
}
__device__ __forceinline__ floatx16 mfma32(short8 a, short8 b, floatx16 c) {
    return __builtin_amdgcn_mfma_f32_32x32x16_bf16(
        __builtin_bit_cast(bf16x8, a), __builtin_bit_cast(bf16x8, b), c, 0, 0, 0);
}

__device__ __forceinline__ void async16(const void* g, void* l) {
    __builtin_amdgcn_global_load_lds(
        (const __attribute__((address_space(1))) void*)g,
        (__attribute__((address_space(3))) void*)l, 16, 0, 0);
}

// ---------------------------------------------------------------------------
// Fused prep (x convert + both weight transposes)
// ---------------------------------------------------------------------------
#define NB_CONV 4096
#define NB_WA   768
#define NB_WP   256

__device__ void transpose_tile(const float* __restrict__ in, unsigned short* __restrict__ out,
                               int K, int N, int kt, int nt, unsigned short (*tile)[65])
{
    const int k0 = kt * 64, n0 = nt * 64;
    const int tr = threadIdx.x >> 4;
    const int tc = (threadIdx.x & 15) * 4;
    #pragma unroll
    for (int it = 0; it < 4; it++) {
        int row = tr + it * 16;
        float4 v = *(const float4*)&in[(size_t)(k0 + row) * N + n0 + tc];
        tile[row][tc + 0] = f2bf(v.x);
        tile[row][tc + 1] = f2bf(v.y);
        tile[row][tc + 2] = f2bf(v.z);
        tile[row][tc + 3] = f2bf(v.w);
    }
    __syncthreads();
    #pragma unroll
    for (int it = 0; it < 4; it++) {
        int nrow = tr + it * 16;
        ushort4 h;
        h.x = tile[tc + 0][nrow]; h.y = tile[tc + 1][nrow];
        h.z = tile[tc + 2][nrow]; h.w = tile[tc + 3][nrow];
        *(ushort4*)&out[(size_t)(n0 + nrow) * K + k0 + tc] = h;
    }
}

__global__ __launch_bounds__(256)
void prep_kernel(const float* __restrict__ x, const float* __restrict__ W_attn,
                 const float* __restrict__ W_proj,
                 unsigned short* __restrict__ xb, unsigned short* __restrict__ Wa_t,
                 unsigned short* __restrict__ Wp_t)
{
    __shared__ unsigned short tile[64][65];
    const int bid = blockIdx.x;
    if (bid < NB_CONV) {
        int i = (bid * 256 + threadIdx.x) * 4;
        float4 v = *(const float4*)&x[i];
        ushort4 h;
        h.x = f2bf(v.x); h.y = f2bf(v.y); h.z = f2bf(v.z); h.w = f2bf(v.w);
        *(ushort4*)&xb[i] = h;
    } else if (bid < NB_CONV + NB_WA) {
        int idx = bid - NB_CONV;
        transpose_tile(W_attn, Wa_t, C_, 3 * C_, idx / 48, idx % 48, tile);
    } else {
        int idx = bid - NB_CONV - NB_WA;
        transpose_tile(W_proj, Wp_t, C_, C_, idx / 16, idx % 16, tile);
    }
}

// ---------------------------------------------------------------------------
// GEMM, 32x32x16 MFMA, BK=64, XOR-swizzled LDS (conflict-free, DMA-compatible)
// ---------------------------------------------------------------------------
template<int MT, bool OUT_BF16, bool VSPLIT>
__global__ __launch_bounds__(256)
void gemm32(const unsigned short* __restrict__ A,
            const unsigned short* __restrict__ Bt,
            void* __restrict__ Cp, unsigned short* __restrict__ vt,
            int M, int N, int K)
{
    constexpr int BK = 64;
    constexpr int BM = 64 * MT;
    __shared__ unsigned short As[BM * BK];
    __shared__ unsigned short Bs[128 * BK];

    const int tid  = threadIdx.x;
    const int lane = tid & 63;
    const int wave = tid >> 6;
    const int l32  = lane & 31;
    const int hi   = lane >> 5;
    const int px   = l32 & 7;
    const int wm   = (wave & 1) * 32 * MT;
    const int wn   = (wave >> 1) * 64;
    const int m0   = blockIdx.y * BM;
    const int n0   = blockIdx.x * 128;

    const int ri = lane >> 3;
    const int pg = lane & 7;
    const int gg = pg ^ ri;

    floatx16 acc[MT][2];
    #pragma unroll
    for (int i = 0; i < MT; i++)
        #pragma unroll
        for (int j = 0; j < 2; j++) acc[i][j] = (floatx16)(0.f);

    const unsigned short* gA = &A[(size_t)(m0 + wave * 8 + ri) * K + gg * 8];
    const unsigned short* gB = &Bt[(size_t)(n0 + wave * 8 + ri) * K + gg * 8];
    unsigned short* lA = &As[(wave * 8) * BK];
    unsigned short* lB = &Bs[(wave * 8) * BK];

    for (int k0 = 0; k0 < K; k0 += BK) {
        #pragma unroll
        for (int s = 0; s < 2 * MT; s++)
            async16(gA + k0 + (size_t)s * 32 * K, lA + s * 32 * BK);
        #pragma unroll
        for (int s = 0; s < 4; s++)
            async16(gB + k0 + (size_t)s * 32 * K, lB + s * 32 * BK);
        __syncthreads();

        #pragma unroll
        for (int ks = 0; ks < 4; ks++) {
            short8 af[MT], bfr[2];
            #pragma unroll
            for (int i = 0; i < MT; i++) {
                int r = wm + i * 32 + l32;
                int p = (ks * 2 + hi) ^ px;
                af[i] = *(const short8*)(&As[r * BK + p * 8]);
            }
            #pragma unroll
            for (int j = 0; j < 2; j++) {
                int r = wn + j * 32 + l32;
                int p = (ks * 2 + hi) ^ px;
                bfr[j] = *(const short8*)(&Bs[r * BK + p * 8]);
            }
            #pragma unroll
            for (int i = 0; i < MT; i++)
                #pragma unroll
                for (int j = 0; j < 2; j++)
                    acc[i][j] = mfma32(af[i], bfr[j], acc[i][j]);
        }
        __syncthreads();
    }

    #pragma unroll
    for (int i = 0; i < MT; i++)
        #pragma unroll
        for (int j = 0; j < 2; j++) {
            const int col  = n0 + wn + j * 32 + l32;
            const int row0 = m0 + wm + i * 32 + 4 * hi;
            if (VSPLIT && col >= 2 * C_) {
                const int hd = col - 2 * C_;
                const int hh = hd >> 6, d = hd & 63;
                #pragma unroll
                for (int g = 0; g < 4; g++) {
                    int rowg = row0 + 8 * g;
                    int bb = rowg >> 11, t = rowg & (T_ - 1);
                    ushort4 h4;
                    h4.x = f2bf(acc[i][j][g * 4 + 0]);
                    h4.y = f2bf(acc[i][j][g * 4 + 1]);
                    h4.z = f2bf(acc[i][j][g * 4 + 2]);
                    h4.w = f2bf(acc[i][j][g * 4 + 3]);
                    *(ushort4*)&vt[((size_t)(bb * NH_ + hh) * 64 + d) * T_ + t] = h4;
                }
            } else {
                #pragma unroll
                for (int g = 0; g < 4; g++)
                    #pragma unroll
                    for (int rr = 0; rr < 4; rr++) {
                        int row = row0 + 8 * g + rr;
                        if (OUT_BF16)
                            ((unsigned short*)Cp)[(size_t)row * N + col] = f2bf(acc[i][j][g * 4 + rr]);
                        else
                            ((float*)Cp)[(size_t)row * N + col] = acc[i][j][g * 4 + rr];
                    }
            }
        }
}

// ---------------------------------------------------------------------------
// Sliding-window attention v3: block = one 64-q tile; K/V tiles DMA-staged
// into XOR-swizzled LDS (coalesced 128-B rows, conflict-free b128 reads),
// shared by 4 waves. XCD-aware block swizzle for L2 window reuse. No running
// max (bounded scores); per-wave P roundtrip; coalesced epilogue.
// LDS granule (row, p) holds global granule p ^ (row & 7).
// ---------------------------------------------------------------------------
__global__ __launch_bounds__(256)
void attn_kernel(const unsigned short* __restrict__ qkv,
                 const unsigned short* __restrict__ vt,
                 unsigned short* __restrict__ y)
{
    __shared__ unsigned short Ks[64 * 64];      // [key][d] swizzled
    __shared__ unsigned short Vs[64 * 64];      // [d][key] swizzled
    __shared__ unsigned short Ps[4][16 * 72];   // per-wave P strip

    const int tid  = threadIdx.x;
    const int lane = tid & 63;
    const int wave = tid >> 6;
    const int l16  = lane & 15;
    const int quad = lane >> 4;
    const int sw   = l16 & 7;                   // fragment swizzle key

    // XCD-aware decode of flat 1024-block grid
    const int g  = blockIdx.x;
    const int yq = g >> 3;
    const int hb = (g & 7) + 8 * (yq >> 5);
    const int qt = yq & 31;
    const int h  = hb & 15;
    const int b  = hb >> 4;

    const int q0b = qt * 64;            // block q-tile base
    const int q0w = q0b + wave * 16;    // this wave's q-base
    const size_t base = (size_t)b * T_;
    const int ROW  = 3 * C_;
    const int qoff = h * HS_;
    const int koff = C_ + h * HS_;
    const size_t vbase = ((size_t)(b * NH_ + h) * 64) * T_;
    unsigned short* Pstrip = Ps[wave];
    const float SC = 0.125f * 1.44269504f;

    // DMA lane mapping: lane = 8*ri + pg ; global granule gg = pg ^ ri
    const int ri = lane >> 3;
    const int gg = (lane & 7) ^ ri;

    // Q a-frags (once)
    short8 aq[2];
    #pragma unroll
    for (int ks = 0; ks < 2; ks++)
        aq[ks] = *(const short8*)&qkv[(base + q0w + l16) * ROW + qoff + ks * 32 + quad * 8];

    floatx4 O[4];
    #pragma unroll
    for (int j = 0; j < 4; j++) O[j] = (floatx4){0.f, 0.f, 0.f, 0.f};
    float psum[4] = {0.f, 0.f, 0.f, 0.f};

    int kb_lo = q0b - (WIN_ - 1);
    kb_lo = (kb_lo > 0 ? kb_lo : 0) & ~63;

    for (int kb = kb_lo; kb <= q0b; kb += 64) {
        __syncthreads();   // all waves done reading previous tile
        // stage K tile: rows wave*16 + c*8 + ri, 128 B each (coalesced)
        #pragma unroll
        for (int c = 0; c < 2; c++) {
            int row = wave * 16 + c * 8;
            async16(&qkv[(base + kb + row + ri) * ROW + koff + gg * 8],
                    &Ks[row * 64]);
            async16(&vt[vbase + (size_t)(row + ri) * T_ + kb + gg * 8],
                    &Vs[row * 64]);
        }
        __syncthreads();   // vmcnt drain -> tiles ready

        // ---- S = Q K^T ----
        floatx4 s[4];
        #pragma unroll
        for (int nt = 0; nt < 4; nt++) s[nt] = (floatx4){0.f, 0.f, 0.f, 0.f};
        #pragma unroll
        for (int ks = 0; ks < 2; ks++)
            #pragma unroll
            for (int nt = 0; nt < 4; nt++) {
                short8 bk = *(const short8*)&Ks[(nt * 16 + l16) * 64
                                                + (((ks * 4 + quad) ^ sw) * 8)];
                s[nt] = mfma16(aq[ks], bk, s[nt]);
            }

        // ---- mask + exp + psum ----
        #pragma unroll
        for (int nt = 0; nt < 4; nt++)
            #pragma unroll
            for (int r = 0; r < 4; r++) {
                int dist = (q0w + quad * 4 + r) - (kb + nt * 16 + l16);
                float sv = ((unsigned)dist < (unsigned)WIN_) ? s[nt][r] * SC : -1e30f;
                float e = exp2f(sv);
                psum[r] += e;
                s[nt][r] = e;
            }

        // ---- P roundtrip (wave-private) ----
        #pragma unroll
        for (int nt = 0; nt < 4; nt++)
            #pragma unroll
            for (int r = 0; r < 4; r++)
                Pstrip[(quad * 4 + r) * 72 + nt * 16 + l16] = f2bf(s[nt][r]);

        // ---- O += P @ V ----
        #pragma unroll
        for (int ks = 0; ks < 2; ks++) {
            short8 ap = *(const short8*)&Pstrip[l16 * 72 + ks * 32 + quad * 8];
            #pragma unroll
            for (int jt = 0; jt < 4; jt++) {
                short8 bv = *(const short8*)&Vs[(jt * 16 + l16) * 64
                                                + (((ks * 4 + quad) ^ sw) * 8)];
                O[jt] = mfma16(ap, bv, O[jt]);
            }
        }
    }

    // ---- row-sum reduce ----
    #pragma unroll
    for (int r = 0; r < 4; r++) {
        #pragma unroll
        for (int off = 8; off >= 1; off >>= 1)
            psum[r] += __shfl_xor(psum[r], off, 64);
    }

    // ---- epilogue via per-wave strip, coalesced ushort8 writes ----
    #pragma unroll
    for (int jt = 0; jt < 4; jt++)
        #pragma unroll
        for (int r = 0; r < 4; r++)
            Pstrip[(quad * 4 + r) * 72 + jt * 16 + l16] = f2bf(O[jt][r] / psum[r]);
    #pragma unroll
    for (int it = 0; it < 2; it++) {
        int c = lane + 64 * it;
        int qr = c >> 3, dc = (c & 7) * 8;
        *(ushortx8*)&y[(base + q0w + qr) * C_ + qoff + dc] =
            *(const ushortx8*)&Pstrip[qr * 72 + dc];
    }
}

// ---------------------------------------------------------------------------
extern "C" void kernel_launch(void* const* d_in, const int* in_sizes, int n_in,
                              void* d_out, int out_size, void* d_ws, size_t ws_size,
                              hipStream_t stream)
{
    const float* x      = (const float*)d_in[0];
    const float* W_attn = (const float*)d_in[1];
    const float* W_proj = (const float*)d_in[2];
    float* out = (float*)d_out;

    unsigned short* xb   = (unsigned short*)d_ws;                 // [M][C]      8 MB
    unsigned short* Wa_t = xb   + (size_t)M_ * C_;                // [3C][C]     6 MB
    unsigned short* Wp_t = Wa_t + (size_t)3 * C_ * C_;            // [C][C]      2 MB
    unsigned short* qkv  = Wp_t + (size_t)C_ * C_;                // [M][3C]    24 MB (Q,K)
    unsigned short* y    = qkv  + (size_t)M_ * 3 * C_;            // [M][C]      8 MB
    unsigned short* vtg  = y    + (size_t)M_ * C_;                // [B][NH][64][T] 8 MB

    dim3 blk(256);
    prep_kernel<<<NB_CONV + NB_WA + NB_WP, blk, 0, stream>>>(x, W_attn, W_proj, xb, Wa_t, Wp_t);
    gemm32<2, true, true><<<dim3((3 * C_) / 128, M_ / 128), blk, 0, stream>>>(
        xb, Wa_t, qkv, vtg, M_, 3 * C_, C_);
    attn_kernel<<<(T_ / 64) * NH_ * B_, blk, 0, stream>>>(qkv, vtg, y);
    gemm32<1, false, false><<<dim3(C_ / 128, M_ / 64), blk, 0, stream>>>(
        y, Wp_t, out, nullptr, M_, C_, C_);
}